// Round 1
// baseline (224.275 us; speedup 1.0000x reference)
//
#include <hip/hip_runtime.h>
#include <hip/hip_bf16.h>
#include <cstdint>
#include <cstddef>

// ---------------- types ----------------
typedef float    f32x4   __attribute__((ext_vector_type(4)));
typedef float    float4v __attribute__((ext_vector_type(4)));
typedef short    short8  __attribute__((ext_vector_type(8)));
typedef __bf16   bf16x8  __attribute__((ext_vector_type(8)));
typedef unsigned short ushort4v __attribute__((ext_vector_type(4)));

// ---------------- problem constants ----------------
constexpr int NB   = 4;      // batch
constexpr int TT   = 2048;   // sequence
constexpr int DD   = 1024;   // model dim (= head dim, single head)
constexpr int MTOT = NB * TT; // 8192 tokens

constexpr int LDSK = 72;     // 64 + 8 bf16 pad -> 144B row stride (9x16B, 2-way bank alias only)

// ---------------- helpers ----------------
__device__ __forceinline__ unsigned short f2bf(float f) {
  union { float f; uint32_t u; } v; v.f = f;
  uint32_t u = v.u;
  uint32_t r = u + 0x7fffu + ((u >> 16) & 1u); // RNE
  return (unsigned short)(r >> 16);
}
__device__ __forceinline__ float bf2f(unsigned short h) {
  union { uint32_t u; float f; } v; v.u = ((uint32_t)h) << 16;
  return v.f;
}

// ---------------- fp32 -> bf16 convert ----------------
__global__ void cvt_kernel(const float* __restrict__ src,
                           unsigned short* __restrict__ dst, int n4) {
  int i = blockIdx.x * blockDim.x + threadIdx.x;
  if (i >= n4) return;
  float4v v = *(const float4v*)(src + (size_t)i * 4);
  ushort4v o;
  o[0] = f2bf(v[0]); o[1] = f2bf(v[1]); o[2] = f2bf(v[2]); o[3] = f2bf(v[3]);
  *(ushort4v*)(dst + (size_t)i * 4) = o;
}

// ---------------- shared bt-GEMM core ----------------
// C[128x128] tile at (row0,col0): A[M,K] row-major (lda), B[N,K] row-major (ldb)
// (i.e. C = A * B^T). 256 threads = 4 waves, each wave 64x64 via 16x16x32 bf16 MFMA.
__device__ __forceinline__ void gemm_tile_bt(
    const unsigned short* __restrict__ A, const unsigned short* __restrict__ Bm,
    int lda, int ldb, int row0, int col0, int kbeg, int kend,
    unsigned short* As, unsigned short* Bs, f32x4 acc[4][4])
{
  const int t = threadIdx.x;
  const int w = t >> 6, l = t & 63;
  const int wr = (w >> 1) * 64, wc = (w & 1) * 64;
  const int lrow = l & 15, lk = (l >> 4) * 8;

  for (int k0 = kbeg; k0 < kend; k0 += 64) {
    // stage A-tile [128][64] and B-tile [128][64] (bf16), 8 bf16 per chunk
    #pragma unroll
    for (int c = 0; c < 4; ++c) {
      int idx = c * 256 + t;       // 0..1023
      int r   = idx >> 3;          // 0..127
      int col = (idx & 7) << 3;    // 0..56
      *(short8*)(As + r * LDSK + col) =
          *(const short8*)(A + (size_t)(row0 + r) * lda + k0 + col);
      *(short8*)(Bs + r * LDSK + col) =
          *(const short8*)(Bm + (size_t)(col0 + r) * ldb + k0 + col);
    }
    __syncthreads();
    #pragma unroll
    for (int kk = 0; kk < 64; kk += 32) {
      bf16x8 av[4], bv[4];
      #pragma unroll
      for (int m = 0; m < 4; ++m)
        av[m] = *(const bf16x8*)(As + (wr + m * 16 + lrow) * LDSK + kk + lk);
      #pragma unroll
      for (int n = 0; n < 4; ++n)
        bv[n] = *(const bf16x8*)(Bs + (wc + n * 16 + lrow) * LDSK + kk + lk);
      #pragma unroll
      for (int m = 0; m < 4; ++m)
        #pragma unroll
        for (int n = 0; n < 4; ++n)
          acc[m][n] = __builtin_amdgcn_mfma_f32_16x16x32_bf16(av[m], bv[n], acc[m][n], 0, 0, 0);
    }
    __syncthreads();
  }
}

// ---------------- QKV projection ----------------
// z=0 -> Q, z=1 -> K, z=2 -> V (stored transposed per batch: vT[b][o][t])
__global__ __launch_bounds__(256) void qkv_gemm(
    const unsigned short* __restrict__ xb,
    const unsigned short* __restrict__ wqb,
    const unsigned short* __restrict__ wkb,
    const unsigned short* __restrict__ wvb,
    unsigned short* __restrict__ qb,
    unsigned short* __restrict__ kb,
    unsigned short* __restrict__ vtb)
{
  __shared__ __align__(16) unsigned short As[128 * LDSK];
  __shared__ __align__(16) unsigned short Bs[128 * LDSK];
  const int which = blockIdx.z;
  const unsigned short* W = (which == 0) ? wqb : (which == 1) ? wkb : wvb;
  const int row0 = blockIdx.y * 128, col0 = blockIdx.x * 128;

  f32x4 acc[4][4];
  #pragma unroll
  for (int m = 0; m < 4; ++m)
    #pragma unroll
    for (int n = 0; n < 4; ++n)
      acc[m][n] = (f32x4){0.f, 0.f, 0.f, 0.f};

  gemm_tile_bt(xb, W, DD, DD, row0, col0, 0, DD, As, Bs, acc);

  const int t = threadIdx.x, w = t >> 6, l = t & 63;
  const int wr = (w >> 1) * 64, wc = (w & 1) * 64;
  #pragma unroll
  for (int m = 0; m < 4; ++m)
    #pragma unroll
    for (int n = 0; n < 4; ++n)
      #pragma unroll
      for (int r = 0; r < 4; ++r) {
        int grow = row0 + wr + m * 16 + (l >> 4) * 4 + r;  // token 0..8191
        int gcol = col0 + wc + n * 16 + (l & 15);          // out-dim 0..1023
        unsigned short hv = f2bf(acc[m][n][r]);
        if (which == 0)      qb[(size_t)grow * DD + gcol] = hv;
        else if (which == 1) kb[(size_t)grow * DD + gcol] = hv;
        else {
          int bb = grow >> 11, tt = grow & 2047;
          vtb[((size_t)bb * DD + gcol) * TT + tt] = hv;    // vT[b][o][t]
        }
      }
}

// ---------------- QK^T (causal, scaled, bf16 logits) ----------------
__global__ __launch_bounds__(256) void qk_gemm(
    const unsigned short* __restrict__ qb,
    const unsigned short* __restrict__ kb,
    unsigned short* __restrict__ Pb)
{
  const int b = blockIdx.z;
  const int row0 = blockIdx.y * 128, col0 = blockIdx.x * 128;
  if (col0 > row0 + 127) return;  // fully masked tile

  __shared__ __align__(16) unsigned short As[128 * LDSK];
  __shared__ __align__(16) unsigned short Bs[128 * LDSK];

  const unsigned short* A = qb + (size_t)b * TT * DD;
  const unsigned short* K = kb + (size_t)b * TT * DD;

  f32x4 acc[4][4];
  #pragma unroll
  for (int m = 0; m < 4; ++m)
    #pragma unroll
    for (int n = 0; n < 4; ++n)
      acc[m][n] = (f32x4){0.f, 0.f, 0.f, 0.f};

  gemm_tile_bt(A, K, DD, DD, row0, col0, 0, DD, As, Bs, acc);

  const float scale = 0.03125f;  // 1/sqrt(1024)
  const int t = threadIdx.x, w = t >> 6, l = t & 63;
  const int wr = (w >> 1) * 64, wc = (w & 1) * 64;
  unsigned short* Prow = Pb + (size_t)b * TT * TT;
  #pragma unroll
  for (int m = 0; m < 4; ++m)
    #pragma unroll
    for (int n = 0; n < 4; ++n)
      #pragma unroll
      for (int r = 0; r < 4; ++r) {
        int grow = row0 + wr + m * 16 + (l >> 4) * 4 + r;
        int gcol = col0 + wc + n * 16 + (l & 15);
        if (gcol <= grow)
          Prow[(size_t)grow * TT + gcol] = f2bf(acc[m][n][r] * scale);
      }
}

// ---------------- row softmax over logits (in place, bf16) ----------------
__global__ __launch_bounds__(256) void softmax_kernel(unsigned short* __restrict__ Pb)
{
  const int q = blockIdx.x, b = blockIdx.y;
  unsigned short* row = Pb + ((size_t)b * TT + q) * TT;
  const int L    = q + 1;                     // valid (unmasked) length
  const int tend = ((q >> 7) + 1) << 7;       // PV reads cols [0, tend)
  const int t = threadIdx.x;

  float mx = -3.0e38f;
  for (int k = t; k < L; k += 256) mx = fmaxf(mx, bf2f(row[k]));
  #pragma unroll
  for (int o = 32; o > 0; o >>= 1) mx = fmaxf(mx, __shfl_down(mx, o));
  __shared__ float redm[4];
  if ((t & 63) == 0) redm[t >> 6] = mx;
  __syncthreads();
  mx = fmaxf(fmaxf(redm[0], redm[1]), fmaxf(redm[2], redm[3]));

  float s = 0.f;
  for (int k = t; k < L; k += 256) s += __expf(bf2f(row[k]) - mx);
  #pragma unroll
  for (int o = 32; o > 0; o >>= 1) s += __shfl_down(s, o);
  __shared__ float reds[4];
  if ((t & 63) == 0) reds[t >> 6] = s;
  __syncthreads();
  s = reds[0] + reds[1] + reds[2] + reds[3];
  const float inv = 1.0f / s;

  for (int k = t; k < tend; k += 256) {
    float p = (k < L) ? __expf(bf2f(row[k]) - mx) * inv : 0.0f;
    row[k] = f2bf(p);
  }
}

// ---------------- PV: O = P * V  (via vT, bt-GEMM), fp32 out ----------------
__global__ __launch_bounds__(256) void pv_gemm(
    const unsigned short* __restrict__ Pb,
    const unsigned short* __restrict__ vtb,
    float* __restrict__ out)
{
  const int b = blockIdx.z;
  const int row0 = blockIdx.y * 128, col0 = blockIdx.x * 128;

  __shared__ __align__(16) unsigned short As[128 * LDSK];
  __shared__ __align__(16) unsigned short Bs[128 * LDSK];

  const unsigned short* A  = Pb  + (size_t)b * TT * TT;   // P [T,T]
  const unsigned short* Bm = vtb + (size_t)b * DD * TT;   // vT [D,T]

  f32x4 acc[4][4];
  #pragma unroll
  for (int m = 0; m < 4; ++m)
    #pragma unroll
    for (int n = 0; n < 4; ++n)
      acc[m][n] = (f32x4){0.f, 0.f, 0.f, 0.f};

  gemm_tile_bt(A, Bm, TT, TT, row0, col0, 0, row0 + 128, As, Bs, acc);

  const int t = threadIdx.x, w = t >> 6, l = t & 63;
  const int wr = (w >> 1) * 64, wc = (w & 1) * 64;
  #pragma unroll
  for (int m = 0; m < 4; ++m)
    #pragma unroll
    for (int n = 0; n < 4; ++n)
      #pragma unroll
      for (int r = 0; r < 4; ++r) {
        int grow = row0 + wr + m * 16 + (l >> 4) * 4 + r;  // q within batch
        int gcol = col0 + wc + n * 16 + (l & 15);          // out-dim
        out[((size_t)b * TT + grow) * DD + gcol] = acc[m][n][r];
      }
}

// ---------------- launch ----------------
extern "C" void kernel_launch(void* const* d_in, const int* in_sizes, int n_in,
                              void* d_out, int out_size, void* d_ws, size_t ws_size,
                              hipStream_t stream) {
  const float* x  = (const float*)d_in[0];
  const float* Wq = (const float*)d_in[1];
  const float* Wk = (const float*)d_in[2];
  const float* Wv = (const float*)d_in[3];
  float* out = (float*)d_out;

  unsigned short* ws  = (unsigned short*)d_ws;
  unsigned short* xb  = ws;                        // 8192*1024
  unsigned short* wqb = xb  + (size_t)MTOT * DD;   // 1024*1024
  unsigned short* wkb = wqb + (size_t)DD * DD;
  unsigned short* wvb = wkb + (size_t)DD * DD;
  unsigned short* qb  = wvb + (size_t)DD * DD;     // 8192*1024
  unsigned short* kb  = qb  + (size_t)MTOT * DD;   // 8192*1024
  unsigned short* vtb = kb  + (size_t)MTOT * DD;   // 4*1024*2048 (vT)
  unsigned short* Pb  = vtb + (size_t)MTOT * DD;   // 4*2048*2048

  // fp32 -> bf16
  {
    int n4x = (MTOT * DD) / 4;      // 2,097,152
    int n4w = (DD * DD) / 4;        // 262,144
    cvt_kernel<<<(n4x + 255) / 256, 256, 0, stream>>>(x,  xb,  n4x);
    cvt_kernel<<<(n4w + 255) / 256, 256, 0, stream>>>(Wq, wqb, n4w);
    cvt_kernel<<<(n4w + 255) / 256, 256, 0, stream>>>(Wk, wkb, n4w);
    cvt_kernel<<<(n4w + 255) / 256, 256, 0, stream>>>(Wv, wvb, n4w);
  }

  qkv_gemm<<<dim3(DD / 128, MTOT / 128, 3), 256, 0, stream>>>(
      xb, wqb, wkb, wvb, qb, kb, vtb);

  qk_gemm<<<dim3(TT / 128, TT / 128, NB), 256, 0, stream>>>(qb, kb, Pb);

  softmax_kernel<<<dim3(TT, NB), 256, 0, stream>>>(Pb);

  pv_gemm<<<dim3(DD / 128, TT / 128, NB), 256, 0, stream>>>(Pb, vtb, out);
}

// Round 2
// 206.091 us; speedup vs baseline: 1.0882x; 1.0882x over previous
//
#include <hip/hip_runtime.h>
#include <hip/hip_bf16.h>
#include <cstdint>
#include <cstddef>

// ---------------- types ----------------
typedef float    f32x4   __attribute__((ext_vector_type(4)));
typedef float    float4v __attribute__((ext_vector_type(4)));
typedef short    short8  __attribute__((ext_vector_type(8)));
typedef __bf16   bf16x8  __attribute__((ext_vector_type(8)));
typedef unsigned short ushort4v __attribute__((ext_vector_type(4)));

// ---------------- problem constants ----------------
constexpr int NB   = 4;       // batch
constexpr int TT   = 2048;    // sequence
constexpr int DD   = 1024;    // model dim (= head dim, single head)
constexpr int MTOT = NB * TT; // 8192 tokens

// ---------------- helpers ----------------
__device__ __forceinline__ unsigned short f2bf(float f) {
  union { float f; uint32_t u; } v; v.f = f;
  uint32_t u = v.u;
  uint32_t r = u + 0x7fffu + ((u >> 16) & 1u); // RNE
  return (unsigned short)(r >> 16);
}
__device__ __forceinline__ float bf2f(unsigned short h) {
  union { uint32_t u; float f; } v; v.u = ((uint32_t)h) << 16;
  return v.f;
}

// ---------------- fp32 -> bf16 convert ----------------
__global__ void cvt_kernel(const float* __restrict__ src,
                           unsigned short* __restrict__ dst, int n4) {
  int i = blockIdx.x * blockDim.x + threadIdx.x;
  if (i >= n4) return;
  float4v v = *(const float4v*)(src + (size_t)i * 4);
  ushort4v o;
  o[0] = f2bf(v[0]); o[1] = f2bf(v[1]); o[2] = f2bf(v[2]); o[3] = f2bf(v[3]);
  *(ushort4v*)(dst + (size_t)i * 4) = o;
}

// ---------------- global -> LDS direct staging (width 16) ----------------
// Stages a 128x64 bf16 tile from row-major (ld) global memory into LINEAR
// LDS [128][64]. global_load_lds: LDS dst = wave-uniform base + lane*16.
// Each wave-iteration covers 8 rows (64 lanes x 16B = 8 x 128B rows).
__device__ __forceinline__ void stage_tile_64(const unsigned short* g0, int ld,
                                              unsigned short* lds, int l, int w) {
  #pragma unroll
  for (int it = 0; it < 4; ++it) {
    const int rbase = ((it << 2) + w) << 3;                 // (it*4 + w) * 8
    const unsigned short* src =
        g0 + (size_t)(rbase + (l >> 3)) * ld + ((l & 7) << 3);
    __builtin_amdgcn_global_load_lds(
        (const __attribute__((address_space(1))) void*)src,
        (__attribute__((address_space(3))) void*)(lds + rbase * 64),
        16, 0, 0);
  }
}

// ---------------- shared bt-GEMM core (m97 structure) ----------------
// C[128x128]: A points at (row0, 0) of A[M,K] row-major (lda); B at (col0, 0)
// of B[N,K] row-major (ldb). C = A * B^T. 256 thr = 4 waves, wave = 64x64.
__device__ __forceinline__ void gemm_core(
    const unsigned short* __restrict__ A, const unsigned short* __restrict__ Bm,
    int lda, int ldb, int kbeg, int kend,
    unsigned short* As, unsigned short* Bs, f32x4 acc[4][4])
{
  const int t = threadIdx.x;
  const int w = t >> 6, l = t & 63;
  const int wr = (w >> 1) * 64, wc = (w & 1) * 64;
  const int lrow = l & 15, lk = (l >> 4) * 8;

  for (int k0 = kbeg; k0 < kend; k0 += 64) {
    stage_tile_64(A + k0, lda, As, l, w);
    stage_tile_64(Bm + k0, ldb, Bs, l, w);
    __syncthreads();   // drains vmcnt (global_load_lds) + barrier
    #pragma unroll
    for (int kk = 0; kk < 64; kk += 32) {
      bf16x8 av[4], bv[4];
      #pragma unroll
      for (int m = 0; m < 4; ++m)
        av[m] = *(const bf16x8*)(As + (wr + m * 16 + lrow) * 64 + kk + lk);
      #pragma unroll
      for (int n = 0; n < 4; ++n)
        bv[n] = *(const bf16x8*)(Bs + (wc + n * 16 + lrow) * 64 + kk + lk);
      #pragma unroll
      for (int m = 0; m < 4; ++m)
        #pragma unroll
        for (int n = 0; n < 4; ++n)
          acc[m][n] = __builtin_amdgcn_mfma_f32_16x16x32_bf16(av[m], bv[n], acc[m][n], 0, 0, 0);
    }
    __syncthreads();
  }
}

// ---------------- QKV projection ----------------
// work decode: which (0=Q,1=K,2=V), row-tile (64), col-tile (8).
// V is written transposed per batch (vT[b][o][t]) via LDS transpose.
__global__ __launch_bounds__(256) void qkv_gemm(
    const unsigned short* __restrict__ xb,
    const unsigned short* __restrict__ wqb,
    const unsigned short* __restrict__ wkb,
    const unsigned short* __restrict__ wvb,
    unsigned short* __restrict__ qb,
    unsigned short* __restrict__ kb,
    unsigned short* __restrict__ vtb)
{
  __shared__ __align__(16) unsigned short smem[17408]; // staging 2x8192; epi 128x136
  unsigned short* As = smem;
  unsigned short* Bs = smem + 8192;

  const int id   = blockIdx.x;                  // 1536 blocks, %8==0
  const int work = (id & 7) * 192 + (id >> 3);  // XCD-contiguous chunks
  const int which = work / 512;
  const int rem   = work - which * 512;
  const int row0  = (rem >> 3) * 128;           // token tile
  const int col0  = (rem & 7) * 128;            // out-dim tile

  const unsigned short* W = (which == 0) ? wqb : (which == 1) ? wkb : wvb;

  f32x4 acc[4][4];
  #pragma unroll
  for (int m = 0; m < 4; ++m)
    #pragma unroll
    for (int n = 0; n < 4; ++n)
      acc[m][n] = (f32x4){0.f, 0.f, 0.f, 0.f};

  gemm_core(xb + (size_t)row0 * DD, W + (size_t)col0 * DD, DD, DD, 0, DD, As, Bs, acc);

  const int t = threadIdx.x, w = t >> 6, l = t & 63;
  const int wr = (w >> 1) * 64, wc = (w & 1) * 64;

  // write accumulator into LDS (transposed for V), then coalesced 16B stores
  unsigned short* Ts = smem;  // [128][136]
  #pragma unroll
  for (int m = 0; m < 4; ++m)
    #pragma unroll
    for (int n = 0; n < 4; ++n)
      #pragma unroll
      for (int r = 0; r < 4; ++r) {
        int rr = wr + m * 16 + (l >> 4) * 4 + r;   // token-local 0..127
        int cc = wc + n * 16 + (l & 15);           // odim-local  0..127
        unsigned short hv = f2bf(acc[m][n][r]);
        if (which == 2) Ts[cc * 136 + rr] = hv;
        else            Ts[rr * 136 + cc] = hv;
      }
  __syncthreads();

  if (which == 2) {
    const int bb = row0 >> 11, t0 = row0 & 2047;
    #pragma unroll
    for (int i = 0; i < 8; ++i) {
      int idx = i * 256 + t;
      int ol  = idx >> 4;            // odim-local row 0..127
      int c16 = (idx & 15) << 3;     // token chunk
      short8 v = *(const short8*)(Ts + ol * 136 + c16);
      *(short8*)(vtb + ((size_t)bb * DD + col0 + ol) * TT + t0 + c16) = v;
    }
  } else {
    unsigned short* dst = (which == 0) ? qb : kb;
    #pragma unroll
    for (int i = 0; i < 8; ++i) {
      int idx = i * 256 + t;
      int rl  = idx >> 4;            // token-local row 0..127
      int c16 = (idx & 15) << 3;     // odim chunk
      short8 v = *(const short8*)(Ts + rl * 136 + c16);
      *(short8*)(dst + (size_t)(row0 + rl) * DD + col0 + c16) = v;
    }
  }
}

// ---------------- QK^T (causal, scaled, bf16 logits) ----------------
// Only lower-triangle tiles launched: 136 per batch, 544 total.
__global__ __launch_bounds__(256) void qk_gemm(
    const unsigned short* __restrict__ qb,
    const unsigned short* __restrict__ kb,
    unsigned short* __restrict__ Pb)
{
  __shared__ __align__(16) unsigned short smem[16384];
  unsigned short* As = smem;
  unsigned short* Bs = smem + 8192;

  const int id   = blockIdx.x;                 // 544 blocks, %8==0
  const int work = (id & 7) * 68 + (id >> 3);
  const int b    = work / 136;
  const int i    = work - b * 136;
  int row = (int)((sqrtf(8.0f * (float)i + 1.0f) - 1.0f) * 0.5f);
  while ((row + 1) * (row + 2) / 2 <= i) ++row;
  while (row * (row + 1) / 2 > i) --row;
  const int col  = i - row * (row + 1) / 2;
  const int row0 = row * 128, col0 = col * 128;

  const unsigned short* A = qb + (size_t)b * TT * DD + (size_t)row0 * DD;
  const unsigned short* K = kb + (size_t)b * TT * DD + (size_t)col0 * DD;

  f32x4 acc[4][4];
  #pragma unroll
  for (int m = 0; m < 4; ++m)
    #pragma unroll
    for (int n = 0; n < 4; ++n)
      acc[m][n] = (f32x4){0.f, 0.f, 0.f, 0.f};

  gemm_core(A, K, DD, DD, 0, DD, As, Bs, acc);

  const float scale = 0.03125f;  // 1/sqrt(1024)
  const int t = threadIdx.x, w = t >> 6, l = t & 63;
  const int wr = (w >> 1) * 64, wc = (w & 1) * 64;
  unsigned short* Prow = Pb + (size_t)b * TT * TT;
  #pragma unroll
  for (int m = 0; m < 4; ++m)
    #pragma unroll
    for (int n = 0; n < 4; ++n)
      #pragma unroll
      for (int r = 0; r < 4; ++r) {
        int grow = row0 + wr + m * 16 + (l >> 4) * 4 + r;
        int gcol = col0 + wc + n * 16 + (l & 15);
        if (gcol <= grow)
          Prow[(size_t)grow * TT + gcol] = f2bf(acc[m][n][r] * scale);
      }
}

// ---------------- row softmax (single pass, vectorized, in place) ----------
// Each thread owns ONE short8 chunk (tend <= 2048 = 256 thr * 8), so the row
// lives in registers: 1 global read + 1 global write.
__global__ __launch_bounds__(256) void softmax_kernel(unsigned short* __restrict__ Pb)
{
  const int q = blockIdx.x, b = blockIdx.y;
  unsigned short* row = Pb + ((size_t)b * TT + q) * TT;
  const int L    = q + 1;                  // valid length
  const int tend = ((q >> 7) + 1) << 7;    // PV reads [0, tend)
  const int t = threadIdx.x;
  const int c0 = t << 3;
  const bool has = c0 < tend;

  float f[8];
  float mx = -3.0e38f;
  if (has) {
    short8 v = *(const short8*)(row + c0);
    #pragma unroll
    for (int j = 0; j < 8; ++j) {
      float x = bf2f((unsigned short)v[j]);
      f[j] = (c0 + j < L) ? x : -3.0e38f;
      mx = fmaxf(mx, f[j]);
    }
  }
  #pragma unroll
  for (int o = 32; o > 0; o >>= 1) mx = fmaxf(mx, __shfl_down(mx, o));
  __shared__ float redm[4];
  if ((t & 63) == 0) redm[t >> 6] = mx;
  __syncthreads();
  mx = fmaxf(fmaxf(redm[0], redm[1]), fmaxf(redm[2], redm[3]));

  float e[8];
  float s = 0.f;
  if (has) {
    #pragma unroll
    for (int j = 0; j < 8; ++j) {
      e[j] = (c0 + j < L) ? __expf(f[j] - mx) : 0.0f;
      s += e[j];
    }
  }
  #pragma unroll
  for (int o = 32; o > 0; o >>= 1) s += __shfl_down(s, o);
  __shared__ float reds[4];
  if ((t & 63) == 0) reds[t >> 6] = s;
  __syncthreads();
  s = reds[0] + reds[1] + reds[2] + reds[3];
  const float inv = 1.0f / s;

  if (has) {
    short8 o8;
    #pragma unroll
    for (int j = 0; j < 8; ++j) o8[j] = (short)f2bf(e[j] * inv);
    *(short8*)(row + c0) = o8;
  }
}

// ---------------- PV: O = P * V (via vT, bt-GEMM), fp32 out ----------------
__global__ __launch_bounds__(256) void pv_gemm(
    const unsigned short* __restrict__ Pb,
    const unsigned short* __restrict__ vtb,
    float* __restrict__ out)
{
  __shared__ __align__(16) unsigned short smem[16384];
  unsigned short* As = smem;
  unsigned short* Bs = smem + 8192;

  const int id   = blockIdx.x;                 // 512 blocks
  const int work = (id & 7) * 64 + (id >> 3);
  const int b    = work >> 7;
  const int rem  = work & 127;
  const int row0 = (rem >> 3) * 128;           // q tile
  const int col0 = (rem & 7) * 128;            // out-dim tile

  const unsigned short* A  = Pb  + (size_t)b * TT * TT + (size_t)row0 * TT;
  const unsigned short* Bm = vtb + (size_t)b * DD * TT + (size_t)col0 * TT;

  f32x4 acc[4][4];
  #pragma unroll
  for (int m = 0; m < 4; ++m)
    #pragma unroll
    for (int n = 0; n < 4; ++n)
      acc[m][n] = (f32x4){0.f, 0.f, 0.f, 0.f};

  gemm_core(A, Bm, TT, TT, 0, row0 + 128, As, Bs, acc);

  const int t = threadIdx.x, w = t >> 6, l = t & 63;
  const int wr = (w >> 1) * 64, wc = (w & 1) * 64;
  #pragma unroll
  for (int m = 0; m < 4; ++m)
    #pragma unroll
    for (int n = 0; n < 4; ++n)
      #pragma unroll
      for (int r = 0; r < 4; ++r) {
        int grow = row0 + wr + m * 16 + (l >> 4) * 4 + r;
        int gcol = col0 + wc + n * 16 + (l & 15);
        out[((size_t)b * TT + grow) * DD + gcol] = acc[m][n][r];
      }
}

// ---------------- launch ----------------
extern "C" void kernel_launch(void* const* d_in, const int* in_sizes, int n_in,
                              void* d_out, int out_size, void* d_ws, size_t ws_size,
                              hipStream_t stream) {
  const float* x  = (const float*)d_in[0];
  const float* Wq = (const float*)d_in[1];
  const float* Wk = (const float*)d_in[2];
  const float* Wv = (const float*)d_in[3];
  float* out = (float*)d_out;

  unsigned short* ws  = (unsigned short*)d_ws;
  unsigned short* xb  = ws;                        // 8192*1024
  unsigned short* wqb = xb  + (size_t)MTOT * DD;   // 1024*1024
  unsigned short* wkb = wqb + (size_t)DD * DD;
  unsigned short* wvb = wkb + (size_t)DD * DD;
  unsigned short* qb  = wvb + (size_t)DD * DD;     // 8192*1024
  unsigned short* kb  = qb  + (size_t)MTOT * DD;   // 8192*1024
  unsigned short* vtb = kb  + (size_t)MTOT * DD;   // 4*1024*2048 (vT)
  unsigned short* Pb  = vtb + (size_t)MTOT * DD;   // 4*2048*2048

  {
    int n4x = (MTOT * DD) / 4;
    int n4w = (DD * DD) / 4;
    cvt_kernel<<<(n4x + 255) / 256, 256, 0, stream>>>(x,  xb,  n4x);
    cvt_kernel<<<(n4w + 255) / 256, 256, 0, stream>>>(Wq, wqb, n4w);
    cvt_kernel<<<(n4w + 255) / 256, 256, 0, stream>>>(Wk, wkb, n4w);
    cvt_kernel<<<(n4w + 255) / 256, 256, 0, stream>>>(Wv, wvb, n4w);
  }

  qkv_gemm<<<dim3(1536), 256, 0, stream>>>(xb, wqb, wkb, wvb, qb, kb, vtb);

  qk_gemm<<<dim3(544), 256, 0, stream>>>(qb, kb, Pb);

  softmax_kernel<<<dim3(TT, NB), 256, 0, stream>>>(Pb);

  pv_gemm<<<dim3(512), 256, 0, stream>>>(Pb, vtb, out);
}

// Round 3
// 153.900 us; speedup vs baseline: 1.4573x; 1.3391x over previous
//
#include <hip/hip_runtime.h>
#include <hip/hip_bf16.h>
#include <cstdint>
#include <cstddef>

// ---------------- types ----------------
typedef float    f32x4   __attribute__((ext_vector_type(4)));
typedef float    float4v __attribute__((ext_vector_type(4)));
typedef short    short8  __attribute__((ext_vector_type(8)));
typedef __bf16   bf16x8  __attribute__((ext_vector_type(8)));
typedef unsigned short ushort4v __attribute__((ext_vector_type(4)));

// ---------------- problem constants ----------------
constexpr int NB   = 4;       // batch
constexpr int TT   = 2048;    // sequence
constexpr int DD   = 1024;    // model dim (= head dim, single head)
constexpr int MTOT = NB * TT; // 8192 tokens

// ---------------- helpers ----------------
__device__ __forceinline__ unsigned short f2bf(float f) {
  union { float f; uint32_t u; } v; v.f = f;
  uint32_t u = v.u;
  uint32_t r = u + 0x7fffu + ((u >> 16) & 1u); // RNE
  return (unsigned short)(r >> 16);
}
__device__ __forceinline__ float bf2f(unsigned short h) {
  union { uint32_t u; float f; } v; v.u = ((uint32_t)h) << 16;
  return v.f;
}

// ---------------- fp32 -> bf16 convert ----------------
__global__ void cvt_kernel(const float* __restrict__ src,
                           unsigned short* __restrict__ dst, int n4) {
  int i = blockIdx.x * blockDim.x + threadIdx.x;
  if (i >= n4) return;
  float4v v = *(const float4v*)(src + (size_t)i * 4);
  ushort4v o;
  o[0] = f2bf(v[0]); o[1] = f2bf(v[1]); o[2] = f2bf(v[2]); o[3] = f2bf(v[3]);
  *(ushort4v*)(dst + (size_t)i * 4) = o;
}

// ---------------- global -> LDS direct staging (width 16, swizzled src) ----
// Stages a 128x64 bf16 tile into LINEAR LDS [128][64]. DMA dest is
// wave-uniform base + lane*16 (rule 21: linear dest). The SOURCE column chunk
// is pre-permuted by the same involution the reads use: chunk' = (l&7)^(l>>3),
// i.e. LDS (row r, halfword c) holds global (r, c ^ ((r&7)<<3)).
__device__ __forceinline__ void stage_tile(const unsigned short* g0, int ld,
                                           unsigned short* lds, int l, int w,
                                           int srcswz) {
  #pragma unroll
  for (int it = 0; it < 4; ++it) {
    const int rbase = ((it << 2) + w) << 3;                 // (it*4 + w) * 8
    const unsigned short* src =
        g0 + (size_t)(rbase + (l >> 3)) * ld + srcswz;
    __builtin_amdgcn_global_load_lds(
        (const __attribute__((address_space(1))) void*)src,
        (__attribute__((address_space(3))) void*)(lds + rbase * 64),
        16, 0, 0);
  }
}

// ---------------- pipelined bt-GEMM core ----------------
// C[128x128]: A at (row0,0) of A[M,K] row-major (lda); B at (col0,0) of
// B[N,K] row-major (ldb). C = A * B^T. 256 thr = 4 waves, wave = 64x64.
// Double-buffered LDS, counted vmcnt(8) (loads span barriers), raw s_barrier
// (no full drain), XOR-swizzled LDS reads (conflict-free), setprio on MFMA.
__device__ __forceinline__ void gemm_core(
    const unsigned short* __restrict__ A, const unsigned short* __restrict__ Bm,
    int lda, int ldb, int kbeg, int kend,
    unsigned short* smem, f32x4 acc[4][4])
{
  const int t = threadIdx.x;
  const int w = t >> 6, l = t & 63;
  const int wr = (w >> 1) * 64, wc = (w & 1) * 64;
  const int lrow = l & 15, lk = (l >> 4) * 8;
  const int swr    = (l & 7) << 3;                 // read-side XOR (halfwords)
  const int srcswz = (((l & 7) ^ (l >> 3)) << 3);  // source-side chunk permute

  unsigned short* A0 = smem;
  unsigned short* B0 = smem + 8192;
  unsigned short* A1 = smem + 16384;
  unsigned short* B1 = smem + 24576;

  const int NT = (kend - kbeg) >> 6;

  // prologue: stage K-tile 0 into buf0 (8 loads/thread, left in flight)
  stage_tile(A + kbeg, lda, A0, l, w, srcswz);
  stage_tile(Bm + kbeg, ldb, B0, l, w, srcswz);

  for (int tt = 0; tt < NT; ++tt) {
    unsigned short* Ac = (tt & 1) ? A1 : A0;
    unsigned short* Bc = (tt & 1) ? B1 : B0;
    if (tt + 1 < NT) {
      unsigned short* An = (tt & 1) ? A0 : A1;
      unsigned short* Bn = (tt & 1) ? B0 : B1;
      const int k1 = kbeg + ((tt + 1) << 6);
      stage_tile(A + k1, lda, An, l, w, srcswz);   // 8 loads for tile t+1
      stage_tile(Bm + k1, ldb, Bn, l, w, srcswz);
      // wait own tile-t loads (8 newest = tile t+1 stay in flight)
      asm volatile("s_waitcnt vmcnt(8)" ::: "memory");
    } else {
      asm volatile("s_waitcnt vmcnt(0)" ::: "memory");
    }
    __builtin_amdgcn_s_barrier();          // all waves' tile-t loads landed
    __builtin_amdgcn_sched_barrier(0);

    #pragma unroll
    for (int kk = 0; kk < 64; kk += 32) {
      bf16x8 av[4], bv[4];
      #pragma unroll
      for (int m = 0; m < 4; ++m)
        av[m] = *(const bf16x8*)(Ac + (wr + m * 16 + lrow) * 64 + ((kk + lk) ^ swr));
      #pragma unroll
      for (int n = 0; n < 4; ++n)
        bv[n] = *(const bf16x8*)(Bc + (wc + n * 16 + lrow) * 64 + ((kk + lk) ^ swr));
      __builtin_amdgcn_s_setprio(1);
      #pragma unroll
      for (int m = 0; m < 4; ++m)
        #pragma unroll
        for (int n = 0; n < 4; ++n)
          acc[m][n] = __builtin_amdgcn_mfma_f32_16x16x32_bf16(av[m], bv[n], acc[m][n], 0, 0, 0);
      __builtin_amdgcn_s_setprio(0);
    }
    __builtin_amdgcn_sched_barrier(0);
    __builtin_amdgcn_s_barrier();          // readers done before next stage
    __builtin_amdgcn_sched_barrier(0);
  }
}

// ---------------- QKV projection ----------------
__global__ __launch_bounds__(256, 2) void qkv_gemm(
    const unsigned short* __restrict__ xb,
    const unsigned short* __restrict__ wqb,
    const unsigned short* __restrict__ wkb,
    const unsigned short* __restrict__ wvb,
    unsigned short* __restrict__ qb,
    unsigned short* __restrict__ kb,
    unsigned short* __restrict__ vtb)
{
  __shared__ __align__(16) unsigned short smem[32768]; // 64 KB: dbuf staging / epi

  const int id   = blockIdx.x;                  // 1536 blocks, %8==0
  const int work = (id & 7) * 192 + (id >> 3);  // XCD-contiguous chunks
  const int which = work / 512;
  const int rem   = work - which * 512;
  const int row0  = (rem >> 3) * 128;           // token tile
  const int col0  = (rem & 7) * 128;            // out-dim tile

  const unsigned short* W = (which == 0) ? wqb : (which == 1) ? wkb : wvb;

  f32x4 acc[4][4];
  #pragma unroll
  for (int m = 0; m < 4; ++m)
    #pragma unroll
    for (int n = 0; n < 4; ++n)
      acc[m][n] = (f32x4){0.f, 0.f, 0.f, 0.f};

  gemm_core(xb + (size_t)row0 * DD, W + (size_t)col0 * DD, DD, DD, 0, DD, smem, acc);

  const int t = threadIdx.x, w = t >> 6, l = t & 63;
  const int wr = (w >> 1) * 64, wc = (w & 1) * 64;

  unsigned short* Ts = smem;  // [128][136]
  #pragma unroll
  for (int m = 0; m < 4; ++m)
    #pragma unroll
    for (int n = 0; n < 4; ++n)
      #pragma unroll
      for (int r = 0; r < 4; ++r) {
        int rr = wr + m * 16 + (l >> 4) * 4 + r;   // token-local 0..127
        int cc = wc + n * 16 + (l & 15);           // odim-local  0..127
        unsigned short hv = f2bf(acc[m][n][r]);
        if (which == 2) Ts[cc * 136 + rr] = hv;
        else            Ts[rr * 136 + cc] = hv;
      }
  __syncthreads();

  if (which == 2) {
    const int bb = row0 >> 11, t0 = row0 & 2047;
    #pragma unroll
    for (int i = 0; i < 8; ++i) {
      int idx = i * 256 + t;
      int ol  = idx >> 4;            // odim-local row 0..127
      int c16 = (idx & 15) << 3;     // token chunk
      short8 v = *(const short8*)(Ts + ol * 136 + c16);
      *(short8*)(vtb + ((size_t)bb * DD + col0 + ol) * TT + t0 + c16) = v;
    }
  } else {
    unsigned short* dst = (which == 0) ? qb : kb;
    #pragma unroll
    for (int i = 0; i < 8; ++i) {
      int idx = i * 256 + t;
      int rl  = idx >> 4;            // token-local row 0..127
      int c16 = (idx & 15) << 3;     // odim chunk
      short8 v = *(const short8*)(Ts + rl * 136 + c16);
      *(short8*)(dst + (size_t)(row0 + rl) * DD + col0 + c16) = v;
    }
  }
}

// ---------------- QK^T (causal, scaled, bf16 logits) ----------------
__global__ __launch_bounds__(256, 2) void qk_gemm(
    const unsigned short* __restrict__ qb,
    const unsigned short* __restrict__ kb,
    unsigned short* __restrict__ Pb)
{
  __shared__ __align__(16) unsigned short smem[32768];

  const int id   = blockIdx.x;                 // 544 blocks, %8==0
  const int work = (id & 7) * 68 + (id >> 3);
  const int b    = work / 136;
  const int i    = work - b * 136;
  int row = (int)((sqrtf(8.0f * (float)i + 1.0f) - 1.0f) * 0.5f);
  while ((row + 1) * (row + 2) / 2 <= i) ++row;
  while (row * (row + 1) / 2 > i) --row;
  const int col  = i - row * (row + 1) / 2;
  const int row0 = row * 128, col0 = col * 128;

  const unsigned short* A = qb + (size_t)b * TT * DD + (size_t)row0 * DD;
  const unsigned short* K = kb + (size_t)b * TT * DD + (size_t)col0 * DD;

  f32x4 acc[4][4];
  #pragma unroll
  for (int m = 0; m < 4; ++m)
    #pragma unroll
    for (int n = 0; n < 4; ++n)
      acc[m][n] = (f32x4){0.f, 0.f, 0.f, 0.f};

  gemm_core(A, K, DD, DD, 0, DD, smem, acc);

  const float scale = 0.03125f;  // 1/sqrt(1024)
  const int t = threadIdx.x, w = t >> 6, l = t & 63;
  const int wr = (w >> 1) * 64, wc = (w & 1) * 64;
  unsigned short* Prow = Pb + (size_t)b * TT * TT;
  #pragma unroll
  for (int m = 0; m < 4; ++m)
    #pragma unroll
    for (int n = 0; n < 4; ++n)
      #pragma unroll
      for (int r = 0; r < 4; ++r) {
        int grow = row0 + wr + m * 16 + (l >> 4) * 4 + r;
        int gcol = col0 + wc + n * 16 + (l & 15);
        if (gcol <= grow)
          Prow[(size_t)grow * TT + gcol] = f2bf(acc[m][n][r] * scale);
      }
}

// ---------------- row softmax (single pass, vectorized, in place) ----------
__global__ __launch_bounds__(256) void softmax_kernel(unsigned short* __restrict__ Pb)
{
  const int q = blockIdx.x, b = blockIdx.y;
  unsigned short* row = Pb + ((size_t)b * TT + q) * TT;
  const int L    = q + 1;                  // valid length
  const int tend = ((q >> 7) + 1) << 7;    // PV reads [0, tend)
  const int t = threadIdx.x;
  const int c0 = t << 3;
  const bool has = c0 < tend;

  float f[8];
  float mx = -3.0e38f;
  if (has) {
    short8 v = *(const short8*)(row + c0);
    #pragma unroll
    for (int j = 0; j < 8; ++j) {
      float x = bf2f((unsigned short)v[j]);
      f[j] = (c0 + j < L) ? x : -3.0e38f;
      mx = fmaxf(mx, f[j]);
    }
  }
  #pragma unroll
  for (int o = 32; o > 0; o >>= 1) mx = fmaxf(mx, __shfl_down(mx, o));
  __shared__ float redm[4];
  if ((t & 63) == 0) redm[t >> 6] = mx;
  __syncthreads();
  mx = fmaxf(fmaxf(redm[0], redm[1]), fmaxf(redm[2], redm[3]));

  float e[8];
  float s = 0.f;
  if (has) {
    #pragma unroll
    for (int j = 0; j < 8; ++j) {
      e[j] = (c0 + j < L) ? __expf(f[j] - mx) : 0.0f;
      s += e[j];
    }
  }
  #pragma unroll
  for (int o = 32; o > 0; o >>= 1) s += __shfl_down(s, o);
  __shared__ float reds[4];
  if ((t & 63) == 0) reds[t >> 6] = s;
  __syncthreads();
  s = reds[0] + reds[1] + reds[2] + reds[3];
  const float inv = 1.0f / s;

  if (has) {
    short8 o8;
    #pragma unroll
    for (int j = 0; j < 8; ++j) o8[j] = (short)f2bf(e[j] * inv);
    *(short8*)(row + c0) = o8;
  }
}

// ---------------- PV: O = P * V (via vT, bt-GEMM), fp32 out ----------------
__global__ __launch_bounds__(256, 2) void pv_gemm(
    const unsigned short* __restrict__ Pb,
    const unsigned short* __restrict__ vtb,
    float* __restrict__ out)
{
  __shared__ __align__(16) unsigned short smem[32768];

  const int id   = blockIdx.x;                 // 512 blocks
  const int work = (id & 7) * 64 + (id >> 3);
  const int b    = work >> 7;
  const int rem  = work & 127;
  const int row0 = (rem >> 3) * 128;           // q tile
  const int col0 = (rem & 7) * 128;            // out-dim tile

  const unsigned short* A  = Pb  + (size_t)b * TT * TT + (size_t)row0 * TT;
  const unsigned short* Bm = vtb + (size_t)b * DD * TT + (size_t)col0 * TT;

  f32x4 acc[4][4];
  #pragma unroll
  for (int m = 0; m < 4; ++m)
    #pragma unroll
    for (int n = 0; n < 4; ++n)
      acc[m][n] = (f32x4){0.f, 0.f, 0.f, 0.f};

  gemm_core(A, Bm, TT, TT, 0, row0 + 128, smem, acc);

  const int t = threadIdx.x, w = t >> 6, l = t & 63;
  const int wr = (w >> 1) * 64, wc = (w & 1) * 64;
  #pragma unroll
  for (int m = 0; m < 4; ++m)
    #pragma unroll
    for (int n = 0; n < 4; ++n)
      #pragma unroll
      for (int r = 0; r < 4; ++r) {
        int grow = row0 + wr + m * 16 + (l >> 4) * 4 + r;
        int gcol = col0 + wc + n * 16 + (l & 15);
        out[((size_t)b * TT + grow) * DD + gcol] = acc[m][n][r];
      }
}

// ---------------- launch ----------------
extern "C" void kernel_launch(void* const* d_in, const int* in_sizes, int n_in,
                              void* d_out, int out_size, void* d_ws, size_t ws_size,
                              hipStream_t stream) {
  const float* x  = (const float*)d_in[0];
  const float* Wq = (const float*)d_in[1];
  const float* Wk = (const float*)d_in[2];
  const float* Wv = (const float*)d_in[3];
  float* out = (float*)d_out;

  unsigned short* ws  = (unsigned short*)d_ws;
  unsigned short* xb  = ws;                        // 8192*1024
  unsigned short* wqb = xb  + (size_t)MTOT * DD;   // 1024*1024
  unsigned short* wkb = wqb + (size_t)DD * DD;
  unsigned short* wvb = wkb + (size_t)DD * DD;
  unsigned short* qb  = wvb + (size_t)DD * DD;     // 8192*1024
  unsigned short* kb  = qb  + (size_t)MTOT * DD;   // 8192*1024
  unsigned short* vtb = kb  + (size_t)MTOT * DD;   // 4*1024*2048 (vT)
  unsigned short* Pb  = vtb + (size_t)MTOT * DD;   // 4*2048*2048

  {
    int n4x = (MTOT * DD) / 4;
    int n4w = (DD * DD) / 4;
    cvt_kernel<<<(n4x + 255) / 256, 256, 0, stream>>>(x,  xb,  n4x);
    cvt_kernel<<<(n4w + 255) / 256, 256, 0, stream>>>(Wq, wqb, n4w);
    cvt_kernel<<<(n4w + 255) / 256, 256, 0, stream>>>(Wk, wkb, n4w);
    cvt_kernel<<<(n4w + 255) / 256, 256, 0, stream>>>(Wv, wvb, n4w);
  }

  qkv_gemm<<<dim3(1536), 256, 0, stream>>>(xb, wqb, wkb, wvb, qb, kb, vtb);

  qk_gemm<<<dim3(544), 256, 0, stream>>>(qb, kb, Pb);

  softmax_kernel<<<dim3(TT, NB), 256, 0, stream>>>(Pb);

  pv_gemm<<<dim3(512), 256, 0, stream>>>(Pb, vtb, out);
}

// Round 4
// 147.236 us; speedup vs baseline: 1.5232x; 1.0453x over previous
//
#include <hip/hip_runtime.h>
#include <hip/hip_bf16.h>
#include <cstdint>
#include <cstddef>

// ---------------- types ----------------
typedef float    f32x4   __attribute__((ext_vector_type(4)));
typedef float    float4v __attribute__((ext_vector_type(4)));
typedef short    short8  __attribute__((ext_vector_type(8)));
typedef __bf16   bf16x8  __attribute__((ext_vector_type(8)));
typedef unsigned short ushort4v __attribute__((ext_vector_type(4)));

// ---------------- problem constants ----------------
constexpr int NB   = 4;       // batch
constexpr int TT   = 2048;    // sequence
constexpr int DD   = 1024;    // model dim (= head dim, single head)
constexpr int MTOT = NB * TT; // 8192 tokens

// ---------------- helpers ----------------
__device__ __forceinline__ unsigned short f2bf(float f) {
  union { float f; uint32_t u; } v; v.f = f;
  uint32_t u = v.u;
  uint32_t r = u + 0x7fffu + ((u >> 16) & 1u); // RNE
  return (unsigned short)(r >> 16);
}
__device__ __forceinline__ float bf2f(unsigned short h) {
  union { uint32_t u; float f; } v; v.u = ((uint32_t)h) << 16;
  return v.f;
}

// ---------------- fused fp32 -> bf16 convert (x, Wq, Wk, Wv in one launch) --
__global__ void cvt_all(const float* __restrict__ x,  const float* __restrict__ wq,
                        const float* __restrict__ wk, const float* __restrict__ wv,
                        unsigned short* __restrict__ xb,  unsigned short* __restrict__ wqb,
                        unsigned short* __restrict__ wkb, unsigned short* __restrict__ wvb) {
  const int NX = (MTOT * DD) / 4;   // 2,097,152
  const int NW = (DD * DD) / 4;     // 262,144
  int i = blockIdx.x * blockDim.x + threadIdx.x;
  const float* s; unsigned short* d; int off;
  if (i < NX)               { s = x;  d = xb;  off = i; }
  else if (i < NX + NW)     { s = wq; d = wqb; off = i - NX; }
  else if (i < NX + 2 * NW) { s = wk; d = wkb; off = i - NX - NW; }
  else if (i < NX + 3 * NW) { s = wv; d = wvb; off = i - NX - 2 * NW; }
  else return;
  float4v v = *(const float4v*)(s + (size_t)off * 4);
  ushort4v o;
  o[0] = f2bf(v[0]); o[1] = f2bf(v[1]); o[2] = f2bf(v[2]); o[3] = f2bf(v[3]);
  *(ushort4v*)(d + (size_t)off * 4) = o;
}

// ============================================================================
// 256x256 / BK=64 / 512-thread phase-split GEMM for the QKV projection.
// LDS: dbuf x (A 256x64 + B 256x64) bf16 = 128 KiB. Linear layout, source-side
// XOR chunk permute + read-side XOR (rule 21 involution pair).
// ============================================================================

// stage half h (rows h*128..h*128+127) of a 256x64 tile; 2 loads/thread
__device__ __forceinline__ void stage_half(const unsigned short* g0, int ld,
                                           unsigned short* lds, int h,
                                           int w, int l, int srcswz) {
  #pragma unroll
  for (int i = 0; i < 2; ++i) {
    const int rbase = h * 128 + i * 64 + w * 8;   // wave-uniform
    const unsigned short* src = g0 + (size_t)(rbase + (l >> 3)) * ld + srcswz;
    __builtin_amdgcn_global_load_lds(
        (const __attribute__((address_space(1))) void*)src,
        (__attribute__((address_space(3))) void*)(lds + rbase * 64),
        16, 0, 0);
  }
}

__global__ __launch_bounds__(512, 2) void qkv_gemm256(
    const unsigned short* __restrict__ xb,
    const unsigned short* __restrict__ wqb,
    const unsigned short* __restrict__ wkb,
    const unsigned short* __restrict__ wvb,
    unsigned short* __restrict__ qb,
    unsigned short* __restrict__ kb,
    unsigned short* __restrict__ vtb)
{
  __shared__ __align__(16) unsigned short smem[65536];   // 128 KiB
  unsigned short* A0 = smem;
  unsigned short* B0 = smem + 16384;
  unsigned short* A1 = smem + 32768;
  unsigned short* B1 = smem + 49152;

  const int id   = blockIdx.x;                  // 384 blocks, %8==0
  const int work = (id & 7) * 48 + (id >> 3);   // XCD-contiguous chunks
  const int which = work >> 7;                  // 0=Q,1=K,2=V
  const int rem   = work & 127;
  const int row0  = (rem >> 2) * 256;           // token tile
  const int col0  = (rem & 3) * 256;            // out-dim tile

  const unsigned short* W = (which == 0) ? wqb : (which == 1) ? wkb : wvb;
  const unsigned short* A = xb + (size_t)row0 * DD;
  const unsigned short* B = W  + (size_t)col0 * DD;

  const int t = threadIdx.x;
  const int w = t >> 6, l = t & 63;
  const int wr = (w >> 2) * 128;                // wave-row base (0 or 128)
  const int wc = (w & 3) * 64;                  // wave-col base
  const int lrow = l & 15, lk = (l >> 4) * 8;
  const int swr    = (l & 7) << 3;
  const int srcswz = (((l & 7) ^ (l >> 3)) << 3);

  f32x4 acc[8][4];
  #pragma unroll
  for (int m = 0; m < 8; ++m)
    #pragma unroll
    for (int n = 0; n < 4; ++n)
      acc[m][n] = (f32x4){0.f, 0.f, 0.f, 0.f};

  constexpr int NT = DD / 64;   // 16

  // prologue: stage all 4 halves of K-tile 0 (8 loads/thread, in flight)
  stage_half(A, DD, A0, 0, w, l, srcswz);
  stage_half(A, DD, A0, 1, w, l, srcswz);
  stage_half(B, DD, B0, 0, w, l, srcswz);
  stage_half(B, DD, B0, 1, w, l, srcswz);

  for (int tt = 0; tt < NT; ++tt) {
    unsigned short* Ac = (tt & 1) ? A1 : A0;
    unsigned short* Bc = (tt & 1) ? B1 : B0;
    unsigned short* An = (tt & 1) ? A0 : A1;
    unsigned short* Bn = (tt & 1) ? B0 : B1;
    const bool pf = (tt + 1 < NT);
    const int k1 = (tt + 1) << 6;

    // ---- phase 0: stage A-h0(t+1) | wait tile-t loads | B-frags + A-pair0 ----
    if (pf) {
      stage_half(A + k1, DD, An, 0, w, l, srcswz);
      asm volatile("s_waitcnt vmcnt(2)" ::: "memory");
    } else {
      asm volatile("s_waitcnt vmcnt(0)" ::: "memory");
    }
    __builtin_amdgcn_s_barrier();          // all waves' tile-t DMA landed
    __builtin_amdgcn_sched_barrier(0);

    bf16x8 bv[4][2];
    #pragma unroll
    for (int n = 0; n < 4; ++n)
      #pragma unroll
      for (int ks = 0; ks < 2; ++ks)
        bv[n][ks] = *(const bf16x8*)(Bc + (wc + n * 16 + lrow) * 64 + ((ks * 32 + lk) ^ swr));

    #pragma unroll
    for (int p = 0; p < 4; ++p) {          // phases 0..3: A-pair p
      if (pf) {
        if (p == 1) stage_half(A + k1, DD, An, 1, w, l, srcswz);
        if (p == 2) stage_half(B + k1, DD, Bn, 0, w, l, srcswz);
        if (p == 3) stage_half(B + k1, DD, Bn, 1, w, l, srcswz);
      }
      bf16x8 av[2][2];
      #pragma unroll
      for (int j = 0; j < 2; ++j)
        #pragma unroll
        for (int ks = 0; ks < 2; ++ks)
          av[j][ks] = *(const bf16x8*)(Ac + (wr + (p * 2 + j) * 16 + lrow) * 64 + ((ks * 32 + lk) ^ swr));
      __builtin_amdgcn_s_setprio(1);
      #pragma unroll
      for (int j = 0; j < 2; ++j)
        #pragma unroll
        for (int n = 0; n < 4; ++n)
          #pragma unroll
          for (int ks = 0; ks < 2; ++ks)
            acc[p * 2 + j][n] = __builtin_amdgcn_mfma_f32_16x16x32_bf16(av[j][ks], bv[n][ks], acc[p * 2 + j][n], 0, 0, 0);
      __builtin_amdgcn_s_setprio(0);
      __builtin_amdgcn_sched_barrier(0);
    }
    __builtin_amdgcn_s_barrier();          // readers done; nxt-buffer free
    __builtin_amdgcn_sched_barrier(0);
  }

  // ---- epilogue: LDS transpose -> coalesced 16B stores ----
  unsigned short* Ts = smem;               // [128][264]
  if (which != 2) {
    unsigned short* dst = (which == 0) ? qb : kb;
    const int halfsel = w >> 2;            // this wave's row-half
    #pragma unroll
    for (int h = 0; h < 2; ++h) {
      __syncthreads();
      if (halfsel == h) {
        #pragma unroll
        for (int m = 0; m < 8; ++m)
          #pragma unroll
          for (int n = 0; n < 4; ++n)
            #pragma unroll
            for (int r = 0; r < 4; ++r) {
              int rr = m * 16 + (l >> 4) * 4 + r;      // 0..127 within half
              int cc = wc + n * 16 + (l & 15);         // 0..255
              Ts[rr * 264 + cc] = f2bf(acc[m][n][r]);
            }
      }
      __syncthreads();
      #pragma unroll
      for (int i = 0; i < 8; ++i) {
        int idx = i * 512 + t;
        int rl  = idx >> 5;                // 0..127
        int c8  = (idx & 31) << 3;         // 0..248
        short8 v = *(const short8*)(Ts + rl * 264 + c8);
        *(short8*)(dst + (size_t)(row0 + h * 128 + rl) * DD + col0 + c8) = v;
      }
    }
  } else {
    const int bb = row0 >> 11, t0 = row0 & 2047;
    const int csel = (w >> 1) & 1;         // this wave's col-half
    #pragma unroll
    for (int h = 0; h < 2; ++h) {
      __syncthreads();
      if (csel == h) {
        #pragma unroll
        for (int m = 0; m < 8; ++m)
          #pragma unroll
          for (int n = 0; n < 4; ++n)
            #pragma unroll
            for (int r = 0; r < 4; ++r) {
              int rr  = wr + m * 16 + (l >> 4) * 4 + r;        // token 0..255
              int ccl = (wc - h * 128) + n * 16 + (l & 15);    // 0..127
              Ts[ccl * 264 + rr] = f2bf(acc[m][n][r]);
            }
      }
      __syncthreads();
      #pragma unroll
      for (int i = 0; i < 8; ++i) {
        int idx = i * 512 + t;
        int ol  = idx >> 5;                // odim-local 0..127
        int c8  = (idx & 31) << 3;         // token chunk 0..248
        short8 v = *(const short8*)(Ts + ol * 264 + c8);
        *(short8*)(vtb + ((size_t)bb * DD + col0 + h * 128 + ol) * TT + t0 + c8) = v;
      }
    }
  }
}

// ============================================================================
// 128x128 / 4-wave pipelined bt-GEMM core (round-3 proven) for qk / pv
// ============================================================================
__device__ __forceinline__ void stage_tile(const unsigned short* g0, int ld,
                                           unsigned short* lds, int l, int w,
                                           int srcswz) {
  #pragma unroll
  for (int it = 0; it < 4; ++it) {
    const int rbase = ((it << 2) + w) << 3;
    const unsigned short* src =
        g0 + (size_t)(rbase + (l >> 3)) * ld + srcswz;
    __builtin_amdgcn_global_load_lds(
        (const __attribute__((address_space(1))) void*)src,
        (__attribute__((address_space(3))) void*)(lds + rbase * 64),
        16, 0, 0);
  }
}

__device__ __forceinline__ void gemm_core(
    const unsigned short* __restrict__ A, const unsigned short* __restrict__ Bm,
    int lda, int ldb, int kbeg, int kend,
    unsigned short* smem, f32x4 acc[4][4])
{
  const int t = threadIdx.x;
  const int w = t >> 6, l = t & 63;
  const int wr = (w >> 1) * 64, wc = (w & 1) * 64;
  const int lrow = l & 15, lk = (l >> 4) * 8;
  const int swr    = (l & 7) << 3;
  const int srcswz = (((l & 7) ^ (l >> 3)) << 3);

  unsigned short* A0 = smem;
  unsigned short* B0 = smem + 8192;
  unsigned short* A1 = smem + 16384;
  unsigned short* B1 = smem + 24576;

  const int NT = (kend - kbeg) >> 6;

  stage_tile(A + kbeg, lda, A0, l, w, srcswz);
  stage_tile(Bm + kbeg, ldb, B0, l, w, srcswz);

  for (int tt = 0; tt < NT; ++tt) {
    unsigned short* Ac = (tt & 1) ? A1 : A0;
    unsigned short* Bc = (tt & 1) ? B1 : B0;
    if (tt + 1 < NT) {
      unsigned short* An = (tt & 1) ? A0 : A1;
      unsigned short* Bn = (tt & 1) ? B0 : B1;
      const int k1 = kbeg + ((tt + 1) << 6);
      stage_tile(A + k1, lda, An, l, w, srcswz);
      stage_tile(Bm + k1, ldb, Bn, l, w, srcswz);
      asm volatile("s_waitcnt vmcnt(8)" ::: "memory");
    } else {
      asm volatile("s_waitcnt vmcnt(0)" ::: "memory");
    }
    __builtin_amdgcn_s_barrier();
    __builtin_amdgcn_sched_barrier(0);

    #pragma unroll
    for (int kk = 0; kk < 64; kk += 32) {
      bf16x8 av[4], bv[4];
      #pragma unroll
      for (int m = 0; m < 4; ++m)
        av[m] = *(const bf16x8*)(Ac + (wr + m * 16 + lrow) * 64 + ((kk + lk) ^ swr));
      #pragma unroll
      for (int n = 0; n < 4; ++n)
        bv[n] = *(const bf16x8*)(Bc + (wc + n * 16 + lrow) * 64 + ((kk + lk) ^ swr));
      __builtin_amdgcn_s_setprio(1);
      #pragma unroll
      for (int m = 0; m < 4; ++m)
        #pragma unroll
        for (int n = 0; n < 4; ++n)
          acc[m][n] = __builtin_amdgcn_mfma_f32_16x16x32_bf16(av[m], bv[n], acc[m][n], 0, 0, 0);
      __builtin_amdgcn_s_setprio(0);
    }
    __builtin_amdgcn_sched_barrier(0);
    __builtin_amdgcn_s_barrier();
    __builtin_amdgcn_sched_barrier(0);
  }
}

// ---------------- QK^T (causal, scaled, bf16 logits) ----------------
__global__ __launch_bounds__(256, 2) void qk_gemm(
    const unsigned short* __restrict__ qb,
    const unsigned short* __restrict__ kb,
    unsigned short* __restrict__ Pb)
{
  __shared__ __align__(16) unsigned short smem[32768];

  const int id   = blockIdx.x;                 // 544 blocks, %8==0
  const int work = (id & 7) * 68 + (id >> 3);
  const int b    = work / 136;
  const int i    = work - b * 136;
  int row = (int)((sqrtf(8.0f * (float)i + 1.0f) - 1.0f) * 0.5f);
  while ((row + 1) * (row + 2) / 2 <= i) ++row;
  while (row * (row + 1) / 2 > i) --row;
  const int col  = i - row * (row + 1) / 2;
  const int row0 = row * 128, col0 = col * 128;

  const unsigned short* A = qb + (size_t)b * TT * DD + (size_t)row0 * DD;
  const unsigned short* K = kb + (size_t)b * TT * DD + (size_t)col0 * DD;

  f32x4 acc[4][4];
  #pragma unroll
  for (int m = 0; m < 4; ++m)
    #pragma unroll
    for (int n = 0; n < 4; ++n)
      acc[m][n] = (f32x4){0.f, 0.f, 0.f, 0.f};

  gemm_core(A, K, DD, DD, 0, DD, smem, acc);

  const float scale = 0.03125f;  // 1/sqrt(1024)
  const int t = threadIdx.x, w = t >> 6, l = t & 63;
  const int wr = (w >> 1) * 64, wc = (w & 1) * 64;
  unsigned short* Prow = Pb + (size_t)b * TT * TT;
  #pragma unroll
  for (int m = 0; m < 4; ++m)
    #pragma unroll
    for (int n = 0; n < 4; ++n)
      #pragma unroll
      for (int r = 0; r < 4; ++r) {
        int grow = row0 + wr + m * 16 + (l >> 4) * 4 + r;
        int gcol = col0 + wc + n * 16 + (l & 15);
        if (gcol <= grow)
          Prow[(size_t)grow * TT + gcol] = f2bf(acc[m][n][r] * scale);
      }
}

// ---------------- row softmax (single pass, vectorized, in place) ----------
__global__ __launch_bounds__(256) void softmax_kernel(unsigned short* __restrict__ Pb)
{
  const int q = blockIdx.x, b = blockIdx.y;
  unsigned short* row = Pb + ((size_t)b * TT + q) * TT;
  const int L    = q + 1;                  // valid length
  const int tend = ((q >> 7) + 1) << 7;    // PV reads [0, tend)
  const int t = threadIdx.x;
  const int c0 = t << 3;
  const bool has = c0 < tend;

  float f[8];
  float mx = -3.0e38f;
  if (has) {
    short8 v = *(const short8*)(row + c0);
    #pragma unroll
    for (int j = 0; j < 8; ++j) {
      float x = bf2f((unsigned short)v[j]);
      f[j] = (c0 + j < L) ? x : -3.0e38f;
      mx = fmaxf(mx, f[j]);
    }
  }
  #pragma unroll
  for (int o = 32; o > 0; o >>= 1) mx = fmaxf(mx, __shfl_down(mx, o));
  __shared__ float redm[4];
  if ((t & 63) == 0) redm[t >> 6] = mx;
  __syncthreads();
  mx = fmaxf(fmaxf(redm[0], redm[1]), fmaxf(redm[2], redm[3]));

  float e[8];
  float s = 0.f;
  if (has) {
    #pragma unroll
    for (int j = 0; j < 8; ++j) {
      e[j] = (c0 + j < L) ? __expf(f[j] - mx) : 0.0f;
      s += e[j];
    }
  }
  #pragma unroll
  for (int o = 32; o > 0; o >>= 1) s += __shfl_down(s, o);
  __shared__ float reds[4];
  if ((t & 63) == 0) reds[t >> 6] = s;
  __syncthreads();
  s = reds[0] + reds[1] + reds[2] + reds[3];
  const float inv = 1.0f / s;

  if (has) {
    short8 o8;
    #pragma unroll
    for (int j = 0; j < 8; ++j) o8[j] = (short)f2bf(e[j] * inv);
    *(short8*)(row + c0) = o8;
  }
}

// ---------------- PV: O = P * V (via vT, bt-GEMM), fp32 out ----------------
__global__ __launch_bounds__(256, 2) void pv_gemm(
    const unsigned short* __restrict__ Pb,
    const unsigned short* __restrict__ vtb,
    float* __restrict__ out)
{
  __shared__ __align__(16) unsigned short smem[32768];

  const int id   = blockIdx.x;                 // 512 blocks
  const int work = (id & 7) * 64 + (id >> 3);
  const int b    = work >> 7;
  const int rem  = work & 127;
  const int row0 = (rem >> 3) * 128;           // q tile
  const int col0 = (rem & 7) * 128;            // out-dim tile

  const unsigned short* A  = Pb  + (size_t)b * TT * TT + (size_t)row0 * TT;
  const unsigned short* Bm = vtb + (size_t)b * DD * TT + (size_t)col0 * TT;

  f32x4 acc[4][4];
  #pragma unroll
  for (int m = 0; m < 4; ++m)
    #pragma unroll
    for (int n = 0; n < 4; ++n)
      acc[m][n] = (f32x4){0.f, 0.f, 0.f, 0.f};

  gemm_core(A, Bm, TT, TT, 0, row0 + 128, smem, acc);

  const int t = threadIdx.x, w = t >> 6, l = t & 63;
  const int wr = (w >> 1) * 64, wc = (w & 1) * 64;
  #pragma unroll
  for (int m = 0; m < 4; ++m)
    #pragma unroll
    for (int n = 0; n < 4; ++n)
      #pragma unroll
      for (int r = 0; r < 4; ++r) {
        int grow = row0 + wr + m * 16 + (l >> 4) * 4 + r;
        int gcol = col0 + wc + n * 16 + (l & 15);
        out[((size_t)b * TT + grow) * DD + gcol] = acc[m][n][r];
      }
}

// ---------------- launch ----------------
extern "C" void kernel_launch(void* const* d_in, const int* in_sizes, int n_in,
                              void* d_out, int out_size, void* d_ws, size_t ws_size,
                              hipStream_t stream) {
  const float* x  = (const float*)d_in[0];
  const float* Wq = (const float*)d_in[1];
  const float* Wk = (const float*)d_in[2];
  const float* Wv = (const float*)d_in[3];
  float* out = (float*)d_out;

  unsigned short* ws  = (unsigned short*)d_ws;
  unsigned short* xb  = ws;                        // 8192*1024
  unsigned short* wqb = xb  + (size_t)MTOT * DD;   // 1024*1024
  unsigned short* wkb = wqb + (size_t)DD * DD;
  unsigned short* wvb = wkb + (size_t)DD * DD;
  unsigned short* qb  = wvb + (size_t)DD * DD;     // 8192*1024
  unsigned short* kb  = qb  + (size_t)MTOT * DD;   // 8192*1024
  unsigned short* vtb = kb  + (size_t)MTOT * DD;   // 4*1024*2048 (vT)
  unsigned short* Pb  = vtb + (size_t)MTOT * DD;   // 4*2048*2048

  {
    const int NX = (MTOT * DD) / 4, NW = (DD * DD) / 4;
    const int ntot = NX + 3 * NW;                  // 2,883,584
    cvt_all<<<(ntot + 255) / 256, 256, 0, stream>>>(x, Wq, Wk, Wv, xb, wqb, wkb, wvb);
  }

  qkv_gemm256<<<dim3(384), 512, 0, stream>>>(xb, wqb, wkb, wvb, qb, kb, vtb);

  qk_gemm<<<dim3(544), 256, 0, stream>>>(qb, kb, Pb);

  softmax_kernel<<<dim3(TT, NB), 256, 0, stream>>>(Pb);

  pv_gemm<<<dim3(512), 256, 0, stream>>>(Pb, vtb, out);
}